// Round 3
// baseline (619.006 us; speedup 1.0000x reference)
//
#include <hip/hip_runtime.h>
#include <math.h>

#define S_TOK 16384
#define DDIM  4096
#define NEXP  64
#define CAP   256
#define NB    256           // S_TOK / 64 token-blocks
#define KT    64
#define NKT   (DDIM / KT)   // 64

// ---------------------------------------------------------------------------
// Kernel 1: fused router GEMM (64x64 tile) + softmax + argmax epilogue.
// A-tile LDS layout: [kc:16][m^(kc<<2):64][j:4]  (j = k low bits)
//   - store: one ds_write_b128 per float4 loaded from global (4/thread/kt)
//   - read:  per 4-k group, 4 b128 with the same XOR -> conflict-free
// Outputs: arg_idx[S], gateval[S] (=1/denom), cnt_part[NB][64], gsum_part[NB][64]
// ---------------------------------------------------------------------------
__global__ __launch_bounds__(256) void gemm_gate_kernel(
    const float* __restrict__ x, const float* __restrict__ wg,
    int* __restrict__ arg_idx, float* __restrict__ gateval,
    int* __restrict__ cnt_part, float* __restrict__ gsum_part)
{
    __shared__ float As[KT * 64];     // [kc][m^(kc<<2)][j]
    __shared__ float Bs[KT * 64];     // [k][e]
    __shared__ float gsum_sh[NEXP];
    __shared__ int   cnt_sh[NEXP];

    const int t  = threadIdx.x;
    const int tx = t & 15;            // expert-dim thread coord (4 experts each)
    const int ty = t >> 4;            // token-dim thread coord (4 tokens each)
    const int blk   = blockIdx.x;
    const int mBase = blk * 64;

    if (t < NEXP) { gsum_sh[t] = 0.f; cnt_sh[t] = 0; }

    float acc[4][4];
#pragma unroll
    for (int i = 0; i < 4; i++)
#pragma unroll
        for (int j = 0; j < 4; j++) acc[i][j] = 0.f;

    float4 aR[4], bR[4];

    auto loadTile = [&](int kt) {
#pragma unroll
        for (int i = 0; i < 4; i++) {
            int idx = i * 256 + t;
            int m = idx >> 4, kc = idx & 15;
            aR[i] = *reinterpret_cast<const float4*>(
                &x[(size_t)(mBase + m) * DDIM + kt * KT + kc * 4]);
            int r = idx >> 4, ec = idx & 15;
            bR[i] = *reinterpret_cast<const float4*>(
                &wg[(size_t)(kt * KT + r) * NEXP + ec * 4]);
        }
    };

    auto storeTile = [&]() {
#pragma unroll
        for (int i = 0; i < 4; i++) {
            int idx = i * 256 + t;
            int m = idx >> 4, kc = idx & 15;
            // one b128 store, XOR-swizzled on m (bijective per kc)
            *reinterpret_cast<float4*>(
                &As[(kc << 8) + ((m ^ (kc << 2)) << 2)]) = aR[i];
            int r = idx >> 4, ec = idx & 15;
            *reinterpret_cast<float4*>(&Bs[r * 64 + ec * 4]) = bR[i];
        }
    };

    loadTile(0);
    for (int kt = 0; kt < NKT; kt++) {
        __syncthreads();
        storeTile();
        __syncthreads();
        if (kt + 1 < NKT) loadTile(kt + 1);
#pragma unroll
        for (int kg = 0; kg < 16; kg++) {
            float4 af[4], bf[4];
#pragma unroll
            for (int mi = 0; mi < 4; mi++)
                af[mi] = *reinterpret_cast<const float4*>(
                    &As[(kg << 8) + ((((ty << 2) + mi) ^ (kg << 2)) << 2)]);
#pragma unroll
            for (int j = 0; j < 4; j++)
                bf[j] = *reinterpret_cast<const float4*>(
                    &Bs[((kg << 2) + j) * 64 + (tx << 2)]);
#pragma unroll
            for (int j = 0; j < 4; j++) {
                float bv[4] = {bf[j].x, bf[j].y, bf[j].z, bf[j].w};
#pragma unroll
                for (int mi = 0; mi < 4; mi++) {
                    const float av = reinterpret_cast<const float*>(&af[mi])[j];
#pragma unroll
                    for (int ei = 0; ei < 4; ei++)
                        acc[mi][ei] = fmaf(av, bv[ei], acc[mi][ei]);
                }
            }
        }
    }

    // -------- epilogue: per-token softmax/argmax across 16 lanes (tx dim) ----
    float rden[4];
    int   bi[4];
#pragma unroll
    for (int mi = 0; mi < 4; mi++) {
        float m_ = acc[mi][0];
        int   b_ = tx * 4;
#pragma unroll
        for (int ei = 1; ei < 4; ei++) {
            if (acc[mi][ei] > m_) { m_ = acc[mi][ei]; b_ = tx * 4 + ei; }
        }
#pragma unroll
        for (int msk = 1; msk <= 8; msk <<= 1) {
            float om = __shfl_xor(m_, msk, 64);
            int   ob = __shfl_xor(b_, msk, 64);
            if (om > m_ || (om == m_ && ob < b_)) { m_ = om; b_ = ob; }
        }
        bi[mi] = b_;
        float s_ = 0.f;
#pragma unroll
        for (int ei = 0; ei < 4; ei++) {
            acc[mi][ei] = __expf(acc[mi][ei] - m_);
            s_ += acc[mi][ei];
        }
#pragma unroll
        for (int msk = 1; msk <= 8; msk <<= 1) s_ += __shfl_xor(s_, msk, 64);
        rden[mi] = 1.f / s_;
    }

    // column (expert) partial sums of gates for me[] statistic
#pragma unroll
    for (int ei = 0; ei < 4; ei++) {
        float c_ = 0.f;
#pragma unroll
        for (int mi = 0; mi < 4; mi++) c_ += acc[mi][ei] * rden[mi];
        c_ += __shfl_xor(c_, 16, 64);
        c_ += __shfl_xor(c_, 32, 64);
        if ((t & 48) == 0) atomicAdd(&gsum_sh[tx * 4 + ei], c_);
    }

    if ((t & 15) == 0) {
#pragma unroll
        for (int mi = 0; mi < 4; mi++) {
            int tok = mBase + ty * 4 + mi;
            arg_idx[tok] = bi[mi];
            gateval[tok] = rden[mi];          // gate of argmax = exp(0)/denom
            atomicAdd(&cnt_sh[bi[mi]], 1);
        }
    }
    __syncthreads();
    if (t < NEXP) {
        gsum_part[blk * NEXP + t] = gsum_sh[t];
        cnt_part[blk * NEXP + t]  = cnt_sh[t];
    }
}

// ---------------------------------------------------------------------------
// Kernel 2: per-expert exclusive prefix over the 256 block counts + loss.
// 256 threads: thread (e = t&63, q = t>>6) owns a quarter of the blocks.
// ---------------------------------------------------------------------------
__global__ __launch_bounds__(256) void scan_kernel(
    const int* __restrict__ cnt_part, const float* __restrict__ gsum_part,
    int* __restrict__ offsets, float* __restrict__ loss_out)
{
    __shared__ int   qs[4][NEXP];
    __shared__ float qg[4][NEXP];
    const int t = threadIdx.x;
    const int e = t & 63, q = t >> 6;

    int   s = 0;
    float g = 0.f;
    for (int i = 0; i < 64; i++) {
        int b = q * 64 + i;
        s += cnt_part[b * NEXP + e];
        g += gsum_part[b * NEXP + e];
    }
    qs[q][e] = s;
    qg[q][e] = g;
    __syncthreads();

    int base = 0;
    for (int q2 = 0; q2 < q; q2++) base += qs[q2][e];
    int run = base;
    for (int i = 0; i < 64; i++) {
        int b = q * 64 + i;
        offsets[b * NEXP + e] = run;
        run += cnt_part[b * NEXP + e];
    }

    if (q == 0) {   // threads 0..63 = one wave
        int   totc = qs[0][e] + qs[1][e] + qs[2][e] + qs[3][e];
        float totg = qg[0][e] + qg[1][e] + qg[2][e] + qg[3][e];
        float lp = (totg / (float)S_TOK) * ((float)totc / (float)S_TOK);
#pragma unroll
        for (int msk = 1; msk < 64; msk <<= 1) lp += __shfl_xor(lp, msk, 64);
        if (t == 0) loss_out[0] = 0.01f * (float)NEXP * lp;
    }
}

// ---------------------------------------------------------------------------
// Kernel 3: per-token rank within its 64-token block -> dispatch slots.
// ---------------------------------------------------------------------------
__global__ __launch_bounds__(64) void dispatch_kernel(
    const int* __restrict__ arg_idx, const float* __restrict__ gateval,
    const int* __restrict__ offsets,
    float* __restrict__ out_gates, float* __restrict__ out_disp)
{
    __shared__ int sh_e[64];
    const int t = threadIdx.x, blk = blockIdx.x;
    const int tok = blk * 64 + t;
    const int e = arg_idx[tok];
    sh_e[t] = e;
    __syncthreads();
    int rank = 0;
    for (int j = 0; j < t; j++) rank += (sh_e[j] == e);
    int loc = offsets[blk * NEXP + e] + rank;
    float gv = 0.f;
    if (loc < CAP) {
        gv = gateval[tok];
        out_disp[e * CAP + loc] = (float)tok;
    }
    out_gates[tok] = gv;
}

__global__ __launch_bounds__(256) void init_kernel(float* __restrict__ out_disp)
{
    int i = blockIdx.x * 256 + threadIdx.x;
    out_disp[i] = -1.0f;
}

// ---------------------------------------------------------------------------
extern "C" void kernel_launch(void* const* d_in, const int* in_sizes, int n_in,
                              void* d_out, int out_size, void* d_ws, size_t ws_size,
                              hipStream_t stream)
{
    const float* x  = (const float*)d_in[0];
    const float* wg = (const float*)d_in[1];

    float* out       = (float*)d_out;
    float* out_loss  = out;                    // [0]
    float* out_gates = out + 1;                // [1 .. S]
    float* out_disp  = out + 1 + S_TOK;        // [1+S .. 1+S+E*CAP)

    char* ws = (char*)d_ws;
    int*   arg_idx   = (int*)(ws);                  // 64 KB
    float* gateval   = (float*)(ws + (64 << 10));   // 64 KB
    int*   cnt_part  = (int*)(ws + (128 << 10));    // 64 KB
    float* gsum_part = (float*)(ws + (192 << 10));  // 64 KB
    int*   offsets   = (int*)(ws + (256 << 10));    // 64 KB

    hipLaunchKernelGGL(init_kernel, dim3(NEXP * CAP / 256), dim3(256), 0, stream,
                       out_disp);
    hipLaunchKernelGGL(gemm_gate_kernel, dim3(NB), dim3(256), 0, stream,
                       x, wg, arg_idx, gateval, cnt_part, gsum_part);
    hipLaunchKernelGGL(scan_kernel, dim3(1), dim3(256), 0, stream,
                       cnt_part, gsum_part, offsets, out_loss);
    hipLaunchKernelGGL(dispatch_kernel, dim3(NB), dim3(64), 0, stream,
                       arg_idx, gateval, offsets, out_gates, out_disp);
}

// Round 6
// 593.257 us; speedup vs baseline: 1.0434x; 1.0434x over previous
//
#include <hip/hip_runtime.h>
#include <math.h>

#define S_TOK 16384
#define DDIM  4096
#define NEXP  64
#define CAP   256
#define NB    256               // 64-token bookkeeping blocks
#define TM    256               // tokens per gemm tile
#define KT    32
#define SPLITS 8
#define KRANGE (DDIM / SPLITS)  // 512
#define NTILE (KRANGE / KT)     // 16
#define MT    (S_TOK / TM)      // 64 m-tiles
#define APAD  260               // padded row stride (floats) for AT

// ---------------------------------------------------------------------------
// Router GEMM, split-K. 256 thr = 32x8 thread grid, 8x8 micro-tile.
// ATOMIC=0: write partial[s][S][E] (ws >= 34 MB). ATOMIC=1: atomicAdd logits.
// ---------------------------------------------------------------------------
template <int ATOMIC>
__global__ __launch_bounds__(256, 2) void gemm_split_kernel(
    const float* __restrict__ x, const float* __restrict__ wg,
    float* __restrict__ outbuf)
{
    __shared__ float AT[KT * APAD];   // [k][tok] transposed, padded
    __shared__ float Bs[KT * NEXP];   // [k][e]

    const int t   = threadIdx.x;
    const int ty  = t >> 3;           // 0..31 token-group (8 tokens each)
    const int tx  = t & 7;            // 0..7 expert-group (8 experts each)
    const int blk = blockIdx.x;
    const int m   = blk & (MT - 1);
    const int s   = blk >> 6;         // split id
    const int mBase = m * TM;
    const int kBase = s * KRANGE;

    float acc[8][8] = {};
    float4 av[8], bv0, bv1;

    auto loadRegs = [&](int tile) {
        const int k0 = kBase + tile * KT;
#pragma unroll
        for (int p = 0; p < 8; p++) {
            int flat = p * 256 + t;           // f4 index into [256 tok][8 f4]
            int tok = flat >> 3, kf = flat & 7;
            av[p] = *reinterpret_cast<const float4*>(
                &x[(size_t)(mBase + tok) * DDIM + k0 + kf * 4]);
        }
        int fl0 = t, fl1 = 256 + t;           // f4 index into [32 k][16 f4]
        bv0 = *reinterpret_cast<const float4*>(
            &wg[(size_t)(k0 + (fl0 >> 4)) * NEXP + (fl0 & 15) * 4]);
        bv1 = *reinterpret_cast<const float4*>(
            &wg[(size_t)(k0 + (fl1 >> 4)) * NEXP + (fl1 & 15) * 4]);
    };

    loadRegs(0);
    for (int tile = 0; tile < NTILE; tile++) {
        __syncthreads();                      // prev compute done reading LDS
        // store regs -> LDS (A transposed)
#pragma unroll
        for (int p = 0; p < 8; p++) {
            int flat = p * 256 + t;
            int tok = flat >> 3, kf = flat & 7;
#pragma unroll
            for (int j = 0; j < 4; j++)
                AT[(kf * 4 + j) * APAD + tok] = (&av[p].x)[j];
        }
        {
            int fl0 = t, fl1 = 256 + t;
            *reinterpret_cast<float4*>(&Bs[(fl0 >> 4) * NEXP + (fl0 & 15) * 4]) = bv0;
            *reinterpret_cast<float4*>(&Bs[(fl1 >> 4) * NEXP + (fl1 & 15) * 4]) = bv1;
        }
        __syncthreads();
        if (tile + 1 < NTILE) loadRegs(tile + 1);   // fly during compute
#pragma unroll
        for (int k = 0; k < KT; k++) {
            float4 a0 = *reinterpret_cast<const float4*>(&AT[k * APAD + ty * 8]);
            float4 a1 = *reinterpret_cast<const float4*>(&AT[k * APAD + ty * 8 + 4]);
            float4 b0 = *reinterpret_cast<const float4*>(&Bs[k * NEXP + tx * 8]);
            float4 b1 = *reinterpret_cast<const float4*>(&Bs[k * NEXP + tx * 8 + 4]);
            float aa[8] = {a0.x, a0.y, a0.z, a0.w, a1.x, a1.y, a1.z, a1.w};
            float bb[8] = {b0.x, b0.y, b0.z, b0.w, b1.x, b1.y, b1.z, b1.w};
#pragma unroll
            for (int i = 0; i < 8; i++)
#pragma unroll
                for (int j = 0; j < 8; j++)
                    acc[i][j] = fmaf(aa[i], bb[j], acc[i][j]);
        }
    }

#pragma unroll
    for (int i = 0; i < 8; i++) {
        size_t row = (size_t)(mBase + ty * 8 + i) * NEXP + tx * 8;
        if (ATOMIC) {
#pragma unroll
            for (int j = 0; j < 8; j++) atomicAdd(&outbuf[row + j], acc[i][j]);
        } else {
            float* dst = outbuf + (size_t)s * (S_TOK * NEXP) + row;
            *reinterpret_cast<float4*>(dst) =
                make_float4(acc[i][0], acc[i][1], acc[i][2], acc[i][3]);
            *reinterpret_cast<float4*>(dst + 4) =
                make_float4(acc[i][4], acc[i][5], acc[i][6], acc[i][7]);
        }
    }
}

// ---------------------------------------------------------------------------
// Per-token softmax/argmax/stats. One token per lane; 256 tokens per block.
// buf: nsplits==1 -> logits[S][E]; else partial[nsplits][S][E] (summed here).
// ---------------------------------------------------------------------------
__global__ __launch_bounds__(256) void softmax_kernel(
    const float* __restrict__ buf, int nsplits,
    int* __restrict__ arg_idx, float* __restrict__ gateval,
    int* __restrict__ cnt_part, float* __restrict__ gsum_blk)
{
    __shared__ int   cnt_sh[4][NEXP];
    __shared__ float gs_sh[NEXP];
    const int t = threadIdx.x;
    const int w = t >> 6, lane = t & 63;
    const int tok = blockIdx.x * 256 + t;

    if (t < NEXP) gs_sh[t] = 0.f;
    cnt_sh[w][lane] = 0;
    __syncthreads();

    float4 r[16];
    {
        const float* p = buf + (size_t)tok * NEXP;
#pragma unroll
        for (int q = 0; q < 16; q++)
            r[q] = *reinterpret_cast<const float4*>(p + q * 4);
    }
    for (int sp = 1; sp < nsplits; sp++) {
        const float* ps = buf + (size_t)sp * (S_TOK * NEXP) + (size_t)tok * NEXP;
#pragma unroll
        for (int q = 0; q < 16; q++) {
            float4 v = *reinterpret_cast<const float4*>(ps + q * 4);
            r[q].x += v.x; r[q].y += v.y; r[q].z += v.z; r[q].w += v.w;
        }
    }

    float m_ = r[0].x; int b_ = 0;
#pragma unroll
    for (int q = 0; q < 16; q++)
#pragma unroll
        for (int j = 0; j < 4; j++) {
            float v = (&r[q].x)[j];
            int e = q * 4 + j;
            if (v > m_) { m_ = v; b_ = e; }   // strict > keeps first occurrence
        }

    float den = 0.f;
#pragma unroll
    for (int q = 0; q < 16; q++)
#pragma unroll
        for (int j = 0; j < 4; j++) {
            float g = __expf((&r[q].x)[j] - m_);
            (&r[q].x)[j] = g;
            den += g;
        }
    float inv = 1.f / den;

    arg_idx[tok] = b_;
    gateval[tok] = inv;                       // gate of argmax = exp(0)/den
    atomicAdd(&cnt_sh[w][b_], 1);

    // per-expert gate sums: wave butterfly per expert (static-indexed)
#pragma unroll
    for (int q = 0; q < 16; q++)
#pragma unroll
        for (int j = 0; j < 4; j++) {
            float v = (&r[q].x)[j] * inv;
#pragma unroll
            for (int msk = 1; msk < 64; msk <<= 1) v += __shfl_xor(v, msk, 64);
            if (lane == 0) atomicAdd(&gs_sh[q * 4 + j], v);
        }

    __syncthreads();
    cnt_part[(blockIdx.x * 4 + w) * NEXP + lane] = cnt_sh[w][lane];
    if (t < NEXP) gsum_blk[blockIdx.x * NEXP + t] = gs_sh[t];
}

// ---------------------------------------------------------------------------
// Per-expert exclusive prefix over 256 block counts + loss.
// ---------------------------------------------------------------------------
__global__ __launch_bounds__(256) void scan_kernel(
    const int* __restrict__ cnt_part, const float* __restrict__ gsum_blk,
    int* __restrict__ offsets, float* __restrict__ loss_out)
{
    __shared__ int qs[4][NEXP];
    const int t = threadIdx.x;
    const int e = t & 63, q = t >> 6;

    int s = 0;
    for (int i = 0; i < 64; i++) s += cnt_part[(q * 64 + i) * NEXP + e];
    qs[q][e] = s;
    __syncthreads();

    int base = 0;
    for (int q2 = 0; q2 < q; q2++) base += qs[q2][e];
    int run = base;
    for (int i = 0; i < 64; i++) {
        int b = q * 64 + i;
        offsets[b * NEXP + e] = run;
        run += cnt_part[b * NEXP + e];
    }

    if (q == 0) {   // threads 0..63 = one wave
        float totg = 0.f;
        for (int i = 0; i < 64; i++) totg += gsum_blk[i * NEXP + e];
        int totc = qs[0][e] + qs[1][e] + qs[2][e] + qs[3][e];
        float lp = (totg / (float)S_TOK) * ((float)totc / (float)S_TOK);
#pragma unroll
        for (int msk = 1; msk < 64; msk <<= 1) lp += __shfl_xor(lp, msk, 64);
        if (t == 0) loss_out[0] = 0.01f * (float)NEXP * lp;
    }
}

// ---------------------------------------------------------------------------
// Per-token rank within its 64-token block -> dispatch slots.
// ---------------------------------------------------------------------------
__global__ __launch_bounds__(64) void dispatch_kernel(
    const int* __restrict__ arg_idx, const float* __restrict__ gateval,
    const int* __restrict__ offsets,
    float* __restrict__ out_gates, float* __restrict__ out_disp)
{
    __shared__ int sh_e[64];
    const int t = threadIdx.x, blk = blockIdx.x;
    const int tok = blk * 64 + t;
    const int e = arg_idx[tok];
    sh_e[t] = e;
    __syncthreads();
    int rank = 0;
    for (int j = 0; j < t; j++) rank += (sh_e[j] == e);
    int loc = offsets[blk * NEXP + e] + rank;
    float gv = 0.f;
    if (loc < CAP) {
        gv = gateval[tok];
        out_disp[e * CAP + loc] = (float)tok;
    }
    out_gates[tok] = gv;
}

__global__ __launch_bounds__(256) void init_disp_kernel(float* __restrict__ p)
{
    p[blockIdx.x * 256 + threadIdx.x] = -1.0f;
}

__global__ __launch_bounds__(256) void zero_kernel(float* __restrict__ p, int n4)
{
    int i = blockIdx.x * 256 + threadIdx.x;
    float4 z = make_float4(0.f, 0.f, 0.f, 0.f);
    for (; i < n4; i += gridDim.x * 256)
        reinterpret_cast<float4*>(p)[i] = z;
}

// ---------------------------------------------------------------------------
extern "C" void kernel_launch(void* const* d_in, const int* in_sizes, int n_in,
                              void* d_out, int out_size, void* d_ws, size_t ws_size,
                              hipStream_t stream)
{
    const float* x  = (const float*)d_in[0];
    const float* wg = (const float*)d_in[1];

    float* out       = (float*)d_out;
    float* out_loss  = out;                 // [0]
    float* out_gates = out + 1;             // [1 .. S]
    float* out_disp  = out + 1 + S_TOK;     // [1+S ..)

    char* ws = (char*)d_ws;
    int*   arg_idx  = (int*)(ws);                   // 64 KB
    float* gateval  = (float*)(ws + (64 << 10));    // 64 KB
    int*   cnt_part = (int*)(ws + (128 << 10));     // 64 KB
    float* gsum_blk = (float*)(ws + (192 << 10));   // 16 KB
    int*   offsets  = (int*)(ws + (208 << 10));     // 64 KB
    float* buf      = (float*)(ws + (512 << 10));   // logits or partials

    const size_t splitBytes = (size_t)SPLITS * S_TOK * NEXP * sizeof(float);
    const bool use_split = ws_size >= (512u << 10) + splitBytes;

    hipLaunchKernelGGL(init_disp_kernel, dim3(NEXP * CAP / 256), dim3(256), 0,
                       stream, out_disp);

    if (use_split) {
        hipLaunchKernelGGL((gemm_split_kernel<0>), dim3(MT * SPLITS), dim3(256),
                           0, stream, x, wg, buf);
        hipLaunchKernelGGL(softmax_kernel, dim3(S_TOK / 256), dim3(256), 0,
                           stream, buf, SPLITS, arg_idx, gateval, cnt_part,
                           gsum_blk);
    } else {
        hipLaunchKernelGGL(zero_kernel, dim3(256), dim3(256), 0, stream,
                           buf, S_TOK * NEXP / 4);
        hipLaunchKernelGGL((gemm_split_kernel<1>), dim3(MT * SPLITS), dim3(256),
                           0, stream, x, wg, buf);
        hipLaunchKernelGGL(softmax_kernel, dim3(S_TOK / 256), dim3(256), 0,
                           stream, buf, 1, arg_idx, gateval, cnt_part,
                           gsum_blk);
    }

    hipLaunchKernelGGL(scan_kernel, dim3(1), dim3(256), 0, stream,
                       cnt_part, gsum_blk, offsets, out_loss);
    hipLaunchKernelGGL(dispatch_kernel, dim3(NB), dim3(64), 0, stream,
                       arg_idx, gateval, offsets, out_gates, out_disp);
}